// Round 1
// baseline (266.525 us; speedup 1.0000x reference)
//
#include <hip/hip_runtime.h>

#define NCOL 1116
#define NLEV 7
#define NT 256

static __device__ __forceinline__ float softf(float c, float t) {
    float m = fabsf(c) - t;
    return m > 0.0f ? copysignf(m, c) : 0.0f;
}

__global__ __launch_bounds__(NT)
void wavelet_kernel(const float* __restrict__ x,
                    const float* __restrict__ thr_ptr,
                    float* __restrict__ out) {
    // Convolution form: ca[o] = sum_s DEC_LO[s] * x[2o+1-s]  (zero-padded x)
    constexpr float DEC_LO[8] = {-0.010597401784997278f,  0.032883011666982945f,
                                  0.030841381835986965f, -0.18703481171888114f,
                                 -0.02798376941698385f,   0.6308807679295904f,
                                  0.7148465705525415f,    0.23037781330885523f};
    constexpr float DEC_HI[8] = {-0.23037781330885523f,   0.7148465705525415f,
                                 -0.6308807679295904f,   -0.02798376941698385f,
                                  0.18703481171888114f,   0.030841381835986965f,
                                 -0.032883011666982945f, -0.010597401784997278f};
    constexpr float REC_LO[8] = { 0.23037781330885523f,   0.7148465705525415f,
                                  0.6308807679295904f,   -0.02798376941698385f,
                                 -0.18703481171888114f,   0.030841381835986965f,
                                  0.032883011666982945f, -0.010597401784997278f};
    constexpr float REC_HI[8] = {-0.010597401784997278f, -0.032883011666982945f,
                                  0.030841381835986965f,  0.18703481171888114f,
                                 -0.02798376941698385f,  -0.6308807679295904f,
                                  0.7148465705525415f,   -0.23037781330885523f};

    // approx lengths per level; out_len = (n+7)>>1
    constexpr int alen[8] = {1116, 561, 284, 145, 76, 41, 24, 15};
    // detail storage offsets (sizes 561,284,145,76,41,24,15 -> total 1146)
    constexpr int doff[7] = {0, 561, 845, 990, 1066, 1107, 1131};

    __shared__ float A[1132];   // 8 pad | 1116 data | 8 pad
    __shared__ float B[578];    // 8 pad | 562 data  | 8 pad
    __shared__ float D[1146];   // all detail coeffs (thresholded)

    const int tid = threadIdx.x;
    const int row = blockIdx.x;
    const float thr = fmaxf(thr_ptr[0], 0.01f);

    float* a0 = A + 8;
    float* b0 = B + 8;

    // ---- load row (16B-aligned: 1116*4 = 4464 = 279*16) ----
    {
        const float4* xr = (const float4*)(x + (size_t)row * NCOL);
        float4* dst = (float4*)a0;   // A+8 => 32B offset, aligned
        for (int i = tid; i < NCOL / 4; i += NT) dst[i] = xr[i];
        if (tid < 8) { A[tid] = 0.0f; a0[NCOL + tid] = 0.0f; }
    }
    __syncthreads();

    // ---- forward DWT, 7 levels ----
    float* cur = a0;
    float* nxt = b0;
    #pragma unroll
    for (int l = 0; l < NLEV; ++l) {
        const int nout = alen[l + 1];
        float* dp = D + doff[l];
        for (int o = tid; o < nout; o += NT) {
            const float* src = cur + 2 * o + 1;
            float lo = 0.0f, hi = 0.0f;
            #pragma unroll
            for (int s = 0; s < 8; ++s) {
                float v = src[-s];
                lo = fmaf(DEC_LO[s], v, lo);
                hi = fmaf(DEC_HI[s], v, hi);
            }
            nxt[o] = lo;
            dp[o] = softf(hi, thr);   // details always thresholded
        }
        if (tid < 8) { nxt[-8 + tid] = 0.0f; nxt[nout + tid] = 0.0f; }
        float* t = cur; cur = nxt; nxt = t;
        __syncthreads();
    }

    // ---- threshold final approx (cur = a7, len 15, lives in B) ----
    if (tid < 15) cur[tid] = softf(cur[tid], thr);
    __syncthreads();

    // ---- inverse DWT, 7 levels ----
    // y[2m]   = REC_LO[0]*ca[m+3]+REC_LO[2]*ca[m+2]+REC_LO[4]*ca[m+1]+REC_LO[6]*ca[m] + (REC_HI ..)*cd
    // y[2m+1] = REC_LO[1]*ca[m+3]+REC_LO[3]*ca[m+2]+REC_LO[5]*ca[m+1]+REC_LO[7]*ca[m] + (REC_HI ..)*cd
    #pragma unroll
    for (int l = NLEV - 1; l >= 0; --l) {
        const int M = alen[l + 1];      // detail length (a truncated to M)
        const float* dp = D + doff[l];
        const int npair = M - 3;        // output length 2M-6
        if (l > 0) {
            for (int m = tid; m < npair; m += NT) {
                float ca0 = cur[m], ca1 = cur[m + 1], ca2 = cur[m + 2], ca3 = cur[m + 3];
                float cd0 = dp[m],  cd1 = dp[m + 1],  cd2 = dp[m + 2],  cd3 = dp[m + 3];
                float y0 = fmaf(REC_LO[0], ca3, fmaf(REC_LO[2], ca2, fmaf(REC_LO[4], ca1, REC_LO[6] * ca0)));
                y0 = fmaf(REC_HI[0], cd3, fmaf(REC_HI[2], cd2, fmaf(REC_HI[4], cd1, fmaf(REC_HI[6], cd0, y0))));
                float y1 = fmaf(REC_LO[1], ca3, fmaf(REC_LO[3], ca2, fmaf(REC_LO[5], ca1, REC_LO[7] * ca0)));
                y1 = fmaf(REC_HI[1], cd3, fmaf(REC_HI[3], cd2, fmaf(REC_HI[5], cd1, fmaf(REC_HI[7], cd0, y1))));
                nxt[2 * m] = y0;
                nxt[2 * m + 1] = y1;
            }
            float* t = cur; cur = nxt; nxt = t;
            __syncthreads();
        } else {
            // final level: write straight to global (pairs are 8B aligned)
            float2* orow = (float2*)(out + (size_t)row * NCOL);
            for (int m = tid; m < npair; m += NT) {
                float ca0 = cur[m], ca1 = cur[m + 1], ca2 = cur[m + 2], ca3 = cur[m + 3];
                float cd0 = dp[m],  cd1 = dp[m + 1],  cd2 = dp[m + 2],  cd3 = dp[m + 3];
                float y0 = fmaf(REC_LO[0], ca3, fmaf(REC_LO[2], ca2, fmaf(REC_LO[4], ca1, REC_LO[6] * ca0)));
                y0 = fmaf(REC_HI[0], cd3, fmaf(REC_HI[2], cd2, fmaf(REC_HI[4], cd1, fmaf(REC_HI[6], cd0, y0))));
                float y1 = fmaf(REC_LO[1], ca3, fmaf(REC_LO[3], ca2, fmaf(REC_LO[5], ca1, REC_LO[7] * ca0)));
                y1 = fmaf(REC_HI[1], cd3, fmaf(REC_HI[3], cd2, fmaf(REC_HI[5], cd1, fmaf(REC_HI[7], cd0, y1))));
                orow[m] = make_float2(y0, y1);
            }
        }
    }
}

extern "C" void kernel_launch(void* const* d_in, const int* in_sizes, int n_in,
                              void* d_out, int out_size, void* d_ws, size_t ws_size,
                              hipStream_t stream) {
    const float* x = (const float*)d_in[0];
    const float* thr = (const float*)d_in[1];
    float* out = (float*)d_out;
    const int nrow = in_sizes[0] / NCOL;
    hipLaunchKernelGGL(wavelet_kernel, dim3(nrow), dim3(NT), 0, stream, x, thr, out);
}